// Round 4
// baseline (679.018 us; speedup 1.0000x reference)
//
#include <hip/hip_runtime.h>
#include <math.h>

#define N_NODES 32768
#define N_EDGES 262144
#define EPS_C 0.24253562503633297f   // 1/sqrt(17)

// ---------------------------------------------------------------------------
// Edge precompute: r, bessel radial basis w/ envelope, unit vectors Y1 [E,4]
// ---------------------------------------------------------------------------
__global__ __launch_bounds__(256) void edge_pre_kernel(
    const float* __restrict__ vectors, float* __restrict__ rbf, float* __restrict__ Y1)
{
    int e = blockIdx.x * 256 + threadIdx.x;
    float x = vectors[e * 3 + 0], y = vectors[e * 3 + 1], z = vectors[e * 3 + 2];
    float r2 = x * x + y * y + z * z + 1e-12f;
    float r = sqrtf(r2);
    float inv = 1.0f / r;
    *(float4*)(Y1 + e * 4) = make_float4(x * inv, y * inv, z * inv, 0.0f);
    float rc = fmaxf(r, 1e-6f);
    float r6 = r2 * r2 * r2;
    float r7 = r6 * r;
    float r8 = r6 * r2;
    float env = (r < 1.0f) ? (1.0f - 28.0f * r6 + 48.0f * r7 - 21.0f * r8) : 0.0f;
    float sc = 1.41421356237309515f * env / rc;
#pragma unroll
    for (int j = 0; j < 8; ++j)
        rbf[e * 8 + j] = sc * sinf((float)(j + 1) * 3.14159265358979323846f * rc);
}

// ---------------------------------------------------------------------------
// Node init: s = embed_s[species]   (v is never read in interaction 0)
// ---------------------------------------------------------------------------
__global__ __launch_bounds__(256) void init_s_kernel(
    const float* __restrict__ embed_s, const int* __restrict__ species,
    float* __restrict__ s)
{
    int idx = blockIdx.x * 256 + threadIdx.x;  // over N*64
    s[idx] = embed_s[species[idx >> 6] * 64 + (idx & 63)];
}

// ---------------------------------------------------------------------------
// CSR build: histogram -> single-block scan -> scatter
// ---------------------------------------------------------------------------
__global__ __launch_bounds__(256) void hist_kernel(
    const int* __restrict__ receivers, int* __restrict__ counts)
{
    int e = blockIdx.x * 256 + threadIdx.x;
    atomicAdd(&counts[receivers[e]], 1);
}

__global__ __launch_bounds__(1024) void scan_kernel(
    const int* __restrict__ counts, int* __restrict__ row_start, int* __restrict__ cursor)
{
    __shared__ int wave_tot[16];
    int tid = threadIdx.x;
    int c[32];
    int sum = 0;
#pragma unroll
    for (int i = 0; i < 32; ++i) { c[i] = counts[tid * 32 + i]; sum += c[i]; }
    int lane = tid & 63, wv = tid >> 6;
    int x = sum;
#pragma unroll
    for (int off = 1; off < 64; off <<= 1) {
        int y = __shfl_up(x, off);
        if (lane >= off) x += y;
    }
    if (lane == 63) wave_tot[wv] = x;
    __syncthreads();
    if (wv == 0 && lane < 16) {
        int t = wave_tot[lane];
#pragma unroll
        for (int off = 1; off < 16; off <<= 1) {
            int y = __shfl_up(t, off);
            if (lane >= off) t += y;
        }
        wave_tot[lane] = t;
    }
    __syncthreads();
    int excl = x - sum + (wv ? wave_tot[wv - 1] : 0);
    int run = excl;
#pragma unroll
    for (int i = 0; i < 32; ++i) {
        row_start[tid * 32 + i] = run;
        cursor[tid * 32 + i] = run;
        run += c[i];
    }
    if (tid == 1023) row_start[32768] = run;
}

__global__ __launch_bounds__(256) void scatter_kernel(
    const int* __restrict__ receivers, int* __restrict__ cursor, int* __restrict__ edge_ids)
{
    int e = blockIdx.x * 256 + threadIdx.x;
    int slot = atomicAdd(&cursor[receivers[e]], 1);
    edge_ids[slot] = e;
}

// ---------------------------------------------------------------------------
// out[f] += sum_g x[g] * W[g*64+f], 8 nodes at a time; W in LDS.
// ---------------------------------------------------------------------------
__device__ __forceinline__ void dot8s(const float* __restrict__ shW,
                                      const float* __restrict__ shx,
                                      int f, float* acc)
{
#pragma unroll 4
    for (int g = 0; g < 64; g += 4) {
        float w0 = shW[(g + 0) * 64 + f];
        float w1 = shW[(g + 1) * 64 + f];
        float w2 = shW[(g + 2) * 64 + f];
        float w3 = shW[(g + 3) * 64 + f];
#pragma unroll
        for (int t = 0; t < 8; ++t) {
            float4 x = *(const float4*)(shx + t * 64 + g);
            acc[t] = fmaf(x.x, w0, acc[t]);
            acc[t] = fmaf(x.y, w1, acc[t]);
            acc[t] = fmaf(x.z, w2, acc[t]);
            acc[t] = fmaf(x.w, w3, acc[t]);
        }
    }
}

// Per-node weight matrices (per-species skip, wave-uniform pointers), global W.
__device__ __forceinline__ void dot8g(const float* const* __restrict__ Wt,
                                      const float* __restrict__ shx,
                                      int f, float* acc)
{
#pragma unroll 2
    for (int g = 0; g < 64; g += 4) {
        float4 x[8];
#pragma unroll
        for (int t = 0; t < 8; ++t) x[t] = *(const float4*)(shx + t * 64 + g);
#pragma unroll
        for (int t = 0; t < 8; ++t) {
            const float* W = Wt[t] + g * 64 + f;
            acc[t] = fmaf(x[t].x, W[0],   acc[t]);
            acc[t] = fmaf(x[t].y, W[64],  acc[t]);
            acc[t] = fmaf(x[t].z, W[128], acc[t]);
            acc[t] = fmaf(x[t].w, W[192], acc[t]);
        }
    }
}

// ---------------------------------------------------------------------------
// Fused interaction kernel: block = 2 waves; each wave owns 8 receiver nodes.
// Gather (CSR, agg in registers) -> linear -> skip -> product -> readout.
// Ping-pong s/v buffers (read s_cur/v_cur, write s_nxt/v_nxt) -> no races,
// no atomics, no agg arrays. Only the shared weight staging needs barriers;
// all x-staging is wave-private LDS (double-buffered halves xb0/xb1).
// ---------------------------------------------------------------------------
__global__ __launch_bounds__(128, 3) void fused_kernel(
    const float* __restrict__ rbf, const float* __restrict__ Y1,
    const int* __restrict__ senders, const int* __restrict__ edge_ids,
    const int* __restrict__ row_start,
    const float* __restrict__ s_cur, const float* __restrict__ v_cur,
    float* __restrict__ s_nxt, float* __restrict__ v_nxt,
    const float* __restrict__ Wr_i,
    const float* __restrict__ Wls, const float* __restrict__ Wlv,
    const float* __restrict__ skip_s, const float* __restrict__ skip_v,
    const float* __restrict__ pw_i,
    const float* __restrict__ Wps, const float* __restrict__ Wpv,
    const float* __restrict__ Wread0, const float* __restrict__ Wr1a,
    const float* __restrict__ Wr1b,
    const int* __restrict__ species, float* __restrict__ out,
    int has_skip, int slot)
{
    __shared__ __align__(16) float shWm[4096];        // shared weight buffer
    __shared__ __align__(16) float shx_all[2][1024];  // per-wave x buffers
    const int wid = threadIdx.x >> 6;
    const int f = threadIdx.x & 63;
    float* xb0 = shx_all[wid];
    float* xb1 = shx_all[wid] + 512;
    const int base = (blockIdx.x * 2 + wid) * 8;

    // ---- stage radial-MLP weights [8,320] into shWm
    for (int idx = threadIdx.x; idx < 640; idx += 128)
        ((float4*)shWm)[idx] = ((const float4*)Wr_i)[idx];
    __syncthreads();

    // ---- gather phase: agg in registers
    float ags[8], agv0[8], agv1[8], agv2[8];
    for (int t = 0; t < 8; ++t) {
        int n = base + t;
        int beg = row_start[n], end = row_start[n + 1];
        float a0 = 0.f, a1 = 0.f, a2 = 0.f, a3 = 0.f;
        int eid = (beg < end) ? edge_ids[beg] : 0;
        int snd = (beg < end) ? senders[eid] : 0;
        for (int p = beg; p < end; ++p) {
            int pn = p + 1;
            int eid_n = (pn < end) ? edge_ids[pn] : 0;
            float4 yv = *(const float4*)(Y1 + (size_t)eid * 4);
            float4 r0 = *(const float4*)(rbf + (size_t)eid * 8);
            float4 r1 = *(const float4*)(rbf + (size_t)eid * 8 + 4);
            float ss = s_cur[(size_t)snd * 64 + f];
            int snd_n = (pn < end) ? senders[eid_n] : 0;

            float rb[8] = {r0.x, r0.y, r0.z, r0.w, r1.x, r1.y, r1.z, r1.w};
            float w0 = 0.f, w1 = 0.f, w2 = 0.f, w3 = 0.f, w4 = 0.f;
#pragma unroll
            for (int j = 0; j < 8; ++j) {
                const float* Wj = shWm + j * 320;
                w0 = fmaf(rb[j], Wj[f], w0);
                w1 = fmaf(rb[j], Wj[64 + f], w1);
                w2 = fmaf(rb[j], Wj[128 + f], w2);
                w3 = fmaf(rb[j], Wj[192 + f], w3);
                w4 = fmaf(rb[j], Wj[256 + f], w4);
            }
            if (!has_skip) {                      // interaction 0: v == 0
                a0 += w0 * ss;
                float ws2 = w2 * ss;
                a1 += ws2 * yv.x; a2 += ws2 * yv.y; a3 += ws2 * yv.z;
            } else {
                float vs0 = v_cur[((size_t)snd * 3 + 0) * 64 + f];
                float vs1 = v_cur[((size_t)snd * 3 + 1) * 64 + f];
                float vs2 = v_cur[((size_t)snd * 3 + 2) * 64 + f];
                float dot = vs0 * yv.x + vs1 * yv.y + vs2 * yv.z;
                a0 += w0 * ss + w1 * dot;
                float c0 = vs1 * yv.z - vs2 * yv.y;
                float c1 = vs2 * yv.x - vs0 * yv.z;
                float c2 = vs0 * yv.y - vs1 * yv.x;
                float ws2 = w2 * ss;
                a1 += ws2 * yv.x + w3 * vs0 + w4 * c0;
                a2 += ws2 * yv.y + w3 * vs1 + w4 * c1;
                a3 += ws2 * yv.z + w3 * vs2 + w4 * c2;
            }
            eid = eid_n; snd = snd_n;
        }
        ags[t] = a0; agv0[t] = a1; agv1[t] = a2; agv2[t] = a3;
    }

    int spec[8];
#pragma unroll
    for (int t = 0; t < 8; ++t) spec[t] = species[base + t];

#define STAGE_W(src) do { \
        __syncthreads(); \
        for (int idx = threadIdx.x; idx < 1024; idx += 128) \
            ((float4*)shWm)[idx] = ((const float4*)(src))[idx]; \
        __syncthreads(); } while (0)

    // ---- s2 = (agg_s * EPS) @ Wls
    STAGE_W(Wls);
#pragma unroll
    for (int t = 0; t < 8; ++t) xb0[t * 64 + f] = ags[t] * EPS_C;
    float s2[8];
#pragma unroll
    for (int t = 0; t < 8; ++t) s2[t] = 0.f;
    dot8s(shWm, xb0, f, s2);

    // ---- v2[k] = (agg_v[k] * EPS) @ Wlv   (alternate wave-private buffers)
    STAGE_W(Wlv);
    float v2[3][8];
#pragma unroll
    for (int t = 0; t < 8; ++t) xb1[t * 64 + f] = agv0[t] * EPS_C;
#pragma unroll
    for (int t = 0; t < 8; ++t) v2[0][t] = 0.f;
    dot8s(shWm, xb1, f, v2[0]);
#pragma unroll
    for (int t = 0; t < 8; ++t) xb0[t * 64 + f] = agv1[t] * EPS_C;
#pragma unroll
    for (int t = 0; t < 8; ++t) v2[1][t] = 0.f;
    dot8s(shWm, xb0, f, v2[1]);
#pragma unroll
    for (int t = 0; t < 8; ++t) xb1[t * 64 + f] = agv2[t] * EPS_C;
#pragma unroll
    for (int t = 0; t < 8; ++t) v2[2][t] = 0.f;
    dot8s(shWm, xb1, f, v2[2]);

    // ---- symmetric product basis (elementwise in channel)
    float ps[8], pvs[8];
#pragma unroll
    for (int t = 0; t < 8; ++t) {
        const float* p = pw_i + spec[t] * 576 + f;
        float p0 = p[0], p1 = p[64], p2 = p[128], p3 = p[192], p4 = p[256];
        float p5 = p[320], p6 = p[384], p7 = p[448], p8 = p[512];
        float x = s2[t];
        float vv = v2[0][t] * v2[0][t] + v2[1][t] * v2[1][t] + v2[2][t] * v2[2][t];
        float x2 = x * x;
        ps[t] = p0 * x + p1 * x2 + p2 * vv + p3 * x2 * x + p4 * x * vv;
        pvs[t] = p5 + p6 * x + p7 * x2 + p8 * vv;
    }

    // ---- s_new = ps @ Wps (+ per-species skip on s_cur), store
    STAGE_W(Wps);
#pragma unroll
    for (int t = 0; t < 8; ++t) xb0[t * 64 + f] = ps[t];
    float s_new[8];
#pragma unroll
    for (int t = 0; t < 8; ++t) s_new[t] = 0.f;
    dot8s(shWm, xb0, f, s_new);
    if (has_skip) {
        const float* Wt[8];
#pragma unroll
        for (int t = 0; t < 8; ++t) Wt[t] = skip_s + spec[t] * 4096;
#pragma unroll
        for (int t = 0; t < 8; ++t) xb1[t * 64 + f] = s_cur[(size_t)(base + t) * 64 + f];
        dot8g(Wt, xb1, f, s_new);   // accumulate skip directly
    }
#pragma unroll
    for (int t = 0; t < 8; ++t) s_nxt[(size_t)(base + t) * 64 + f] = s_new[t];

    // ---- readout (wave-local; slot selects column of [N,2])
    if (!has_skip) {
        float w0 = Wread0[f];
#pragma unroll
        for (int t = 0; t < 8; ++t) {
            float a = s_new[t] * w0;
            for (int off = 32; off; off >>= 1) a += __shfl_down(a, off);
            if (f == 0) out[(size_t)(base + t) * 2 + slot] = a;
        }
    } else {
#pragma unroll
        for (int t = 0; t < 8; ++t) xb0[t * 64 + f] = s_new[t];
        int hh = f & 15;
        int t0 = f >> 4;
        int t1 = 4 + (f >> 4);
        float a0 = 0.f, a1 = 0.f;
        for (int g = 0; g < 64; ++g) {
            float wa = Wr1a[g * 16 + hh];
            a0 = fmaf(xb0[t0 * 64 + g], wa, a0);
            a1 = fmaf(xb0[t1 * 64 + g], wa, a1);
        }
        float wb = Wr1b[hh];
        float r0 = (a0 / (1.f + expf(-a0))) * wb;
        float r1 = (a1 / (1.f + expf(-a1))) * wb;
        for (int off = 8; off; off >>= 1) {
            r0 += __shfl_down(r0, off);
            r1 += __shfl_down(r1, off);
        }
        if ((f & 15) == 0) {
            out[(size_t)(base + t0) * 2 + slot] = r0;
            out[(size_t)(base + t1) * 2 + slot] = r1;
        }
    }

    // ---- v_new[k] = (pvs*v2[k]) @ Wpv (+ skip on v_cur), store
    STAGE_W(Wpv);
    const float* Wtv[8];
    if (has_skip) {
#pragma unroll
        for (int t = 0; t < 8; ++t) Wtv[t] = skip_v + spec[t] * 4096;
    }
    for (int k = 0; k < 3; ++k) {
#pragma unroll
        for (int t = 0; t < 8; ++t) xb0[t * 64 + f] = pvs[t] * v2[k][t];
        float acc[8];
#pragma unroll
        for (int t = 0; t < 8; ++t) acc[t] = 0.f;
        dot8s(shWm, xb0, f, acc);
        if (has_skip) {
#pragma unroll
            for (int t = 0; t < 8; ++t)
                xb1[t * 64 + f] = v_cur[((size_t)(base + t) * 3 + k) * 64 + f];
            dot8g(Wtv, xb1, f, acc);
        }
#pragma unroll
        for (int t = 0; t < 8; ++t)
            v_nxt[((size_t)(base + t) * 3 + k) * 64 + f] = acc[t];
    }
#undef STAGE_W
}

// ---------------------------------------------------------------------------
extern "C" void kernel_launch(void* const* d_in, const int* in_sizes, int n_in,
                              void* d_out, int out_size, void* d_ws, size_t ws_size,
                              hipStream_t stream)
{
    const float* vectors = (const float*)d_in[0];
    const float* embed_s = (const float*)d_in[1];
    const float* Wr      = (const float*)d_in[2];   // [2,8,320]
    const float* Wls     = (const float*)d_in[3];   // [2,64,64]
    const float* Wlv     = (const float*)d_in[4];
    const float* skip_s  = (const float*)d_in[5];   // [10,64,64]
    const float* skip_v  = (const float*)d_in[6];
    const float* pw      = (const float*)d_in[7];   // [2,10,9,64]
    const float* Wps     = (const float*)d_in[8];
    const float* Wpv     = (const float*)d_in[9];
    const float* Wread0  = (const float*)d_in[10];  // [64,1]
    const float* Wr1a    = (const float*)d_in[11];  // [64,16]
    const float* Wr1b    = (const float*)d_in[12];  // [16,1]
    const int* senders   = (const int*)d_in[13];
    const int* receivers = (const int*)d_in[14];
    const int* species   = (const int*)d_in[15];
    float* out = (float*)d_out;

    // workspace layout (floats / ints)
    float* ws = (float*)d_ws;
    float* rbf  = ws; ws += (size_t)N_EDGES * 8;    // 8 MB
    float* Y1   = ws; ws += (size_t)N_EDGES * 4;    // 4 MB (padded)
    float* sA   = ws; ws += (size_t)N_NODES * 64;   // 8 MB
    float* vA   = ws; ws += (size_t)N_NODES * 192;  // 24 MB  [N,3,64]
    float* sB   = ws; ws += (size_t)N_NODES * 64;   // 8 MB
    float* vB   = ws; ws += (size_t)N_NODES * 192;  // 24 MB
    int* counts    = (int*)ws; ws += N_NODES;       // 128 KB
    int* row_start = (int*)ws; ws += N_NODES + 4;
    int* cursor    = (int*)ws; ws += N_NODES;
    int* edge_ids  = (int*)ws; ws += N_EDGES;       // 1 MB

    edge_pre_kernel<<<N_EDGES / 256, 256, 0, stream>>>(vectors, rbf, Y1);
    init_s_kernel<<<N_NODES * 64 / 256, 256, 0, stream>>>(embed_s, species, sA);

    // CSR build (once; reused by both interactions)
    hipMemsetAsync(counts, 0, N_NODES * sizeof(int), stream);
    hist_kernel<<<N_EDGES / 256, 256, 0, stream>>>(receivers, counts);
    scan_kernel<<<1, 1024, 0, stream>>>(counts, row_start, cursor);
    scatter_kernel<<<N_EDGES / 256, 256, 0, stream>>>(receivers, cursor, edge_ids);

    // interaction 0: read sA (v unused), write sB/vB
    fused_kernel<<<N_NODES / 16, 128, 0, stream>>>(
        rbf, Y1, senders, edge_ids, row_start,
        sA, vA, sB, vB,
        Wr, Wls, Wlv, skip_s, skip_v, pw, Wps, Wpv,
        Wread0, Wr1a, Wr1b, species, out, 0, 0);

    // interaction 1: read sB/vB, write sA/vA
    fused_kernel<<<N_NODES / 16, 128, 0, stream>>>(
        rbf, Y1, senders, edge_ids, row_start,
        sB, vB, sA, vA,
        Wr + 2560, Wls + 4096, Wlv + 4096, skip_s, skip_v,
        pw + 5760, Wps + 4096, Wpv + 4096,
        Wread0, Wr1a, Wr1b, species, out, 1, 1);
}

// Round 5
// 531.477 us; speedup vs baseline: 1.2776x; 1.2776x over previous
//
#include <hip/hip_runtime.h>
#include <math.h>

#define N_NODES 32768
#define N_EDGES 262144
#define EPS_C 0.24253562503633297f   // 1/sqrt(17)

// ---------------------------------------------------------------------------
// Edge precompute: r, bessel radial basis w/ envelope, unit vectors Y1 [E,4]
// ---------------------------------------------------------------------------
__global__ __launch_bounds__(256) void edge_pre_kernel(
    const float* __restrict__ vectors, float* __restrict__ rbf, float* __restrict__ Y1)
{
    int e = blockIdx.x * 256 + threadIdx.x;
    float x = vectors[e * 3 + 0], y = vectors[e * 3 + 1], z = vectors[e * 3 + 2];
    float r2 = x * x + y * y + z * z + 1e-12f;
    float r = sqrtf(r2);
    float inv = 1.0f / r;
    *(float4*)(Y1 + e * 4) = make_float4(x * inv, y * inv, z * inv, 0.0f);
    float rc = fmaxf(r, 1e-6f);
    float r6 = r2 * r2 * r2;
    float r7 = r6 * r;
    float r8 = r6 * r2;
    float env = (r < 1.0f) ? (1.0f - 28.0f * r6 + 48.0f * r7 - 21.0f * r8) : 0.0f;
    float sc = 1.41421356237309515f * env / rc;
#pragma unroll
    for (int j = 0; j < 8; ++j)
        rbf[e * 8 + j] = sc * sinf((float)(j + 1) * 3.14159265358979323846f * rc);
}

// ---------------------------------------------------------------------------
// Node init: s = embed_s[species]; v = 0
// ---------------------------------------------------------------------------
__global__ __launch_bounds__(256) void init_kernel(
    const float* __restrict__ embed_s, const int* __restrict__ species,
    float* __restrict__ s, float* __restrict__ v)
{
    int idx = blockIdx.x * 256 + threadIdx.x;  // over N*64
    int n = idx >> 6, f = idx & 63;
    s[idx] = embed_s[species[n] * 64 + f];
    v[((size_t)n * 3 + 0) * 64 + f] = 0.0f;
    v[((size_t)n * 3 + 1) * 64 + f] = 0.0f;
    v[((size_t)n * 3 + 2) * 64 + f] = 0.0f;
}

// ---------------------------------------------------------------------------
// CSR build: histogram -> single-block scan -> scatter
// ---------------------------------------------------------------------------
__global__ __launch_bounds__(256) void hist_kernel(
    const int* __restrict__ receivers, int* __restrict__ counts)
{
    int e = blockIdx.x * 256 + threadIdx.x;
    atomicAdd(&counts[receivers[e]], 1);
}

__global__ __launch_bounds__(1024) void scan_kernel(
    const int* __restrict__ counts, int* __restrict__ row_start, int* __restrict__ cursor)
{
    __shared__ int wave_tot[16];
    int tid = threadIdx.x;
    int c[32];
    int sum = 0;
#pragma unroll
    for (int i = 0; i < 32; ++i) { c[i] = counts[tid * 32 + i]; sum += c[i]; }
    int lane = tid & 63, wv = tid >> 6;
    int x = sum;
#pragma unroll
    for (int off = 1; off < 64; off <<= 1) {
        int y = __shfl_up(x, off);
        if (lane >= off) x += y;
    }
    if (lane == 63) wave_tot[wv] = x;
    __syncthreads();
    if (wv == 0 && lane < 16) {
        int t = wave_tot[lane];
#pragma unroll
        for (int off = 1; off < 16; off <<= 1) {
            int y = __shfl_up(t, off);
            if (lane >= off) t += y;
        }
        wave_tot[lane] = t;
    }
    __syncthreads();
    int excl = x - sum + (wv ? wave_tot[wv - 1] : 0);
    int run = excl;
#pragma unroll
    for (int i = 0; i < 32; ++i) {
        row_start[tid * 32 + i] = run;
        cursor[tid * 32 + i] = run;
        run += c[i];
    }
    if (tid == 1023) row_start[32768] = run;
}

__global__ __launch_bounds__(256) void scatter_kernel(
    const int* __restrict__ receivers, int* __restrict__ cursor, int* __restrict__ edge_ids)
{
    int e = blockIdx.x * 256 + threadIdx.x;
    int slot = atomicAdd(&cursor[receivers[e]], 1);
    edge_ids[slot] = e;
}

// ---------------------------------------------------------------------------
// Gather edge kernel: wave (64 lanes = channels) owns 4 receiver nodes;
// grid 2048 blocks -> 8 blocks/CU, ~32 waves/CU for latency hiding.
// ---------------------------------------------------------------------------
__global__ __launch_bounds__(256) void gather_kernel(
    const float* __restrict__ rbf, const float* __restrict__ Y1,
    const int* __restrict__ senders, const int* __restrict__ edge_ids,
    const int* __restrict__ row_start,
    const float* __restrict__ s, const float* __restrict__ v,
    const float* __restrict__ Wr_i,       // [8, 320]
    float* __restrict__ agg_s, float* __restrict__ agg_v,
    int vzero)
{
    __shared__ float shW[2560];
    for (int idx = threadIdx.x; idx < 2560; idx += 256) shW[idx] = Wr_i[idx];
    __syncthreads();

    const int wid = threadIdx.x >> 6;
    const int f = threadIdx.x & 63;
    const int base = (blockIdx.x * 4 + wid) * 4;

    for (int t = 0; t < 4; ++t) {
        int n = base + t;
        int beg = row_start[n], end = row_start[n + 1];
        float a0 = 0.f, a1 = 0.f, a2 = 0.f, a3 = 0.f;
        int eid = (beg < end) ? edge_ids[beg] : 0;
        int snd = (beg < end) ? senders[eid] : 0;
        for (int p = beg; p < end; ++p) {
            int pn = p + 1;
            int eid_n = (pn < end) ? edge_ids[pn] : 0;
            float4 yv = *(const float4*)(Y1 + (size_t)eid * 4);
            float4 r0 = *(const float4*)(rbf + (size_t)eid * 8);
            float4 r1 = *(const float4*)(rbf + (size_t)eid * 8 + 4);
            float ss = s[(size_t)snd * 64 + f];
            int snd_n = (pn < end) ? senders[eid_n] : 0;

            float rb[8] = {r0.x, r0.y, r0.z, r0.w, r1.x, r1.y, r1.z, r1.w};
            float w0 = 0.f, w1 = 0.f, w2 = 0.f, w3 = 0.f, w4 = 0.f;
#pragma unroll
            for (int j = 0; j < 8; ++j) {
                const float* Wj = shW + j * 320;
                w0 = fmaf(rb[j], Wj[f], w0);
                w1 = fmaf(rb[j], Wj[64 + f], w1);
                w2 = fmaf(rb[j], Wj[128 + f], w2);
                w3 = fmaf(rb[j], Wj[192 + f], w3);
                w4 = fmaf(rb[j], Wj[256 + f], w4);
            }
            if (vzero) {
                a0 += w0 * ss;
                float ws2 = w2 * ss;
                a1 += ws2 * yv.x; a2 += ws2 * yv.y; a3 += ws2 * yv.z;
            } else {
                float vs0 = v[((size_t)snd * 3 + 0) * 64 + f];
                float vs1 = v[((size_t)snd * 3 + 1) * 64 + f];
                float vs2 = v[((size_t)snd * 3 + 2) * 64 + f];
                float dot = vs0 * yv.x + vs1 * yv.y + vs2 * yv.z;
                a0 += w0 * ss + w1 * dot;
                float c0 = vs1 * yv.z - vs2 * yv.y;
                float c1 = vs2 * yv.x - vs0 * yv.z;
                float c2 = vs0 * yv.y - vs1 * yv.x;
                float ws2 = w2 * ss;
                a1 += ws2 * yv.x + w3 * vs0 + w4 * c0;
                a2 += ws2 * yv.y + w3 * vs1 + w4 * c1;
                a3 += ws2 * yv.z + w3 * vs2 + w4 * c2;
            }
            eid = eid_n; snd = snd_n;
        }
        agg_s[(size_t)n * 64 + f] = a0;
        agg_v[((size_t)n * 3 + 0) * 64 + f] = a1;
        agg_v[((size_t)n * 3 + 1) * 64 + f] = a2;
        agg_v[((size_t)n * 3 + 2) * 64 + f] = a3;
    }
}

// ---------------------------------------------------------------------------
// out[f] += sum_g x[g] * W[g*64+f], 4 nodes at a time; W in LDS, x broadcast.
// ---------------------------------------------------------------------------
__device__ __forceinline__ void dot4s(const float* __restrict__ shW,
                                      const float* __restrict__ shx,
                                      int f, float* acc)
{
#pragma unroll 4
    for (int g = 0; g < 64; g += 4) {
        float w0 = shW[(g + 0) * 64 + f];
        float w1 = shW[(g + 1) * 64 + f];
        float w2 = shW[(g + 2) * 64 + f];
        float w3 = shW[(g + 3) * 64 + f];
#pragma unroll
        for (int t = 0; t < 4; ++t) {
            float4 x = *(const float4*)(shx + t * 64 + g);
            acc[t] = fmaf(x.x, w0, acc[t]);
            acc[t] = fmaf(x.y, w1, acc[t]);
            acc[t] = fmaf(x.z, w2, acc[t]);
            acc[t] = fmaf(x.w, w3, acc[t]);
        }
    }
}

// Per-node weight matrices (per-species skip), weights from global (L2).
__device__ __forceinline__ void dot4g(const float* const* __restrict__ Wt,
                                      const float* __restrict__ shx,
                                      int f, float* acc)
{
#pragma unroll 4
    for (int g = 0; g < 64; g += 4) {
        float4 x[4];
#pragma unroll
        for (int t = 0; t < 4; ++t) x[t] = *(const float4*)(shx + t * 64 + g);
#pragma unroll
        for (int t = 0; t < 4; ++t) {
            const float* W = Wt[t] + g * 64 + f;
            acc[t] = fmaf(x[t].x, W[0],   acc[t]);
            acc[t] = fmaf(x[t].y, W[64],  acc[t]);
            acc[t] = fmaf(x[t].z, W[128], acc[t]);
            acc[t] = fmaf(x[t].w, W[192], acc[t]);
        }
    }
}

// ---------------------------------------------------------------------------
// Node kernel: block = 4 waves x 4 nodes; grid 2048 (8 blocks/CU issued,
// 6 resident by LDS). Only shared-weight staging synchronizes (4 pairs);
// x-staging is wave-private LDS with no barriers. s/v updated in-place.
// ---------------------------------------------------------------------------
__global__ __launch_bounds__(256, 4) void node_kernel(
    const float* __restrict__ agg_s, const float* __restrict__ agg_v,
    float* __restrict__ s, float* __restrict__ v,
    const float* __restrict__ Wls, const float* __restrict__ Wlv,
    const float* __restrict__ skip_s, const float* __restrict__ skip_v,
    const float* __restrict__ pw_i, const float* __restrict__ Wps,
    const float* __restrict__ Wpv,
    const float* __restrict__ Wread0, const float* __restrict__ Wr1a,
    const float* __restrict__ Wr1b,
    const int* __restrict__ species, float* __restrict__ out,
    int has_skip, int mode, int slot)
{
    const int wid = threadIdx.x >> 6;
    const int f = threadIdx.x & 63;
    const int base = (blockIdx.x * 4 + wid) * 4;
    __shared__ __align__(16) float shWm[4096];          // shared 64x64 weight
    __shared__ __align__(16) float shx_all[4][512];     // per-wave x, 2 halves
    float* xb0 = shx_all[wid];
    float* xb1 = shx_all[wid] + 256;

#define STAGE_W(src) do { \
        __syncthreads(); \
        for (int idx = threadIdx.x; idx < 1024; idx += 256) \
            ((float4*)shWm)[idx] = ((const float4*)(src))[idx]; \
        __syncthreads(); } while (0)

    int spec[4];
#pragma unroll
    for (int t = 0; t < 4; ++t) spec[t] = species[base + t];

    // prefetch agg into registers (in flight across the first staging barrier)
    float ags[4], agv0[4], agv1[4], agv2[4];
#pragma unroll
    for (int t = 0; t < 4; ++t) {
        ags[t]  = agg_s[(size_t)(base + t) * 64 + f];
        agv0[t] = agg_v[((size_t)(base + t) * 3 + 0) * 64 + f];
        agv1[t] = agg_v[((size_t)(base + t) * 3 + 1) * 64 + f];
        agv2[t] = agg_v[((size_t)(base + t) * 3 + 2) * 64 + f];
    }

    // ---- s2 = (agg_s * EPS) @ Wls
    STAGE_W(Wls);
#pragma unroll
    for (int t = 0; t < 4; ++t) xb0[t * 64 + f] = ags[t] * EPS_C;
    float s2[4] = {0.f, 0.f, 0.f, 0.f};
    dot4s(shWm, xb0, f, s2);

    // ---- v2[k] = (agg_v[k] * EPS) @ Wlv  (alternating wave-private halves)
    STAGE_W(Wlv);
    float v2[3][4];
#pragma unroll
    for (int t = 0; t < 4; ++t) xb1[t * 64 + f] = agv0[t] * EPS_C;
#pragma unroll
    for (int t = 0; t < 4; ++t) v2[0][t] = 0.f;
    dot4s(shWm, xb1, f, v2[0]);
#pragma unroll
    for (int t = 0; t < 4; ++t) xb0[t * 64 + f] = agv1[t] * EPS_C;
#pragma unroll
    for (int t = 0; t < 4; ++t) v2[1][t] = 0.f;
    dot4s(shWm, xb0, f, v2[1]);
#pragma unroll
    for (int t = 0; t < 4; ++t) xb1[t * 64 + f] = agv2[t] * EPS_C;
#pragma unroll
    for (int t = 0; t < 4; ++t) v2[2][t] = 0.f;
    dot4s(shWm, xb1, f, v2[2]);

    // ---- symmetric product basis (elementwise in channel)
    float ps[4], pvs[4];
#pragma unroll
    for (int t = 0; t < 4; ++t) {
        const float* p = pw_i + spec[t] * 576 + f;
        float p0 = p[0], p1 = p[64], p2 = p[128], p3 = p[192], p4 = p[256];
        float p5 = p[320], p6 = p[384], p7 = p[448], p8 = p[512];
        float x = s2[t];
        float vv = v2[0][t] * v2[0][t] + v2[1][t] * v2[1][t] + v2[2][t] * v2[2][t];
        float x2 = x * x;
        ps[t] = p0 * x + p1 * x2 + p2 * vv + p3 * x2 * x + p4 * x * vv;
        pvs[t] = p5 + p6 * x + p7 * x2 + p8 * vv;
    }

    // ---- s_new = ps @ Wps (+ per-species skip on pre-interaction s)
    STAGE_W(Wps);
#pragma unroll
    for (int t = 0; t < 4; ++t) xb0[t * 64 + f] = ps[t];
    float s_new[4] = {0.f, 0.f, 0.f, 0.f};
    dot4s(shWm, xb0, f, s_new);
    if (has_skip) {
        const float* Wt[4];
#pragma unroll
        for (int t = 0; t < 4; ++t) Wt[t] = skip_s + spec[t] * 4096;
#pragma unroll
        for (int t = 0; t < 4; ++t) xb1[t * 64 + f] = s[(size_t)(base + t) * 64 + f];
        dot4g(Wt, xb1, f, s_new);
    }
#pragma unroll
    for (int t = 0; t < 4; ++t) s[(size_t)(base + t) * 64 + f] = s_new[t];

    // ---- readout (wave-local)
    if (mode == 0) {
        float w0 = Wread0[f];
#pragma unroll
        for (int t = 0; t < 4; ++t) {
            float a = s_new[t] * w0;
            for (int off = 32; off; off >>= 1) a += __shfl_down(a, off);
            if (f == 0) out[(size_t)(base + t) * 2 + slot] = a;
        }
    } else {
#pragma unroll
        for (int t = 0; t < 4; ++t) xb0[t * 64 + f] = s_new[t];
        int hh = f & 15;
        int t0 = f >> 4;             // 4 nodes x 16 hidden = 64 lanes exactly
        float a0 = 0.f;
        for (int g = 0; g < 64; ++g)
            a0 = fmaf(xb0[t0 * 64 + g], Wr1a[g * 16 + hh], a0);
        float r0 = (a0 / (1.f + expf(-a0))) * Wr1b[hh];
        for (int off = 8; off; off >>= 1) r0 += __shfl_down(r0, off);
        if (hh == 0) out[(size_t)(base + t0) * 2 + slot] = r0;
    }

    // ---- v_new[k] = (pvs * v2[k]) @ Wpv (+ skip on pre-interaction v)
    STAGE_W(Wpv);
    const float* Wtv[4];
    if (has_skip) {
#pragma unroll
        for (int t = 0; t < 4; ++t) Wtv[t] = skip_v + spec[t] * 4096;
    }
    for (int k = 0; k < 3; ++k) {
#pragma unroll
        for (int t = 0; t < 4; ++t) xb0[t * 64 + f] = pvs[t] * v2[k][t];
        float acc[4] = {0.f, 0.f, 0.f, 0.f};
        dot4s(shWm, xb0, f, acc);
        if (has_skip) {
#pragma unroll
            for (int t = 0; t < 4; ++t)
                xb1[t * 64 + f] = v[((size_t)(base + t) * 3 + k) * 64 + f];
            dot4g(Wtv, xb1, f, acc);
        }
#pragma unroll
        for (int t = 0; t < 4; ++t)
            v[((size_t)(base + t) * 3 + k) * 64 + f] = acc[t];
    }
#undef STAGE_W
}

// ---------------------------------------------------------------------------
extern "C" void kernel_launch(void* const* d_in, const int* in_sizes, int n_in,
                              void* d_out, int out_size, void* d_ws, size_t ws_size,
                              hipStream_t stream)
{
    const float* vectors = (const float*)d_in[0];
    const float* embed_s = (const float*)d_in[1];
    const float* Wr      = (const float*)d_in[2];   // [2,8,320]
    const float* Wls     = (const float*)d_in[3];   // [2,64,64]
    const float* Wlv     = (const float*)d_in[4];
    const float* skip_s  = (const float*)d_in[5];   // [10,64,64]
    const float* skip_v  = (const float*)d_in[6];
    const float* pw      = (const float*)d_in[7];   // [2,10,9,64]
    const float* Wps     = (const float*)d_in[8];
    const float* Wpv     = (const float*)d_in[9];
    const float* Wread0  = (const float*)d_in[10];  // [64,1]
    const float* Wr1a    = (const float*)d_in[11];  // [64,16]
    const float* Wr1b    = (const float*)d_in[12];  // [16,1]
    const int* senders   = (const int*)d_in[13];
    const int* receivers = (const int*)d_in[14];
    const int* species   = (const int*)d_in[15];
    float* out = (float*)d_out;

    // workspace layout (floats / ints)
    float* ws = (float*)d_ws;
    float* rbf   = ws; ws += (size_t)N_EDGES * 8;   // 8 MB
    float* Y1    = ws; ws += (size_t)N_EDGES * 4;   // 4 MB (padded)
    float* s     = ws; ws += (size_t)N_NODES * 64;  // 8 MB
    float* v     = ws; ws += (size_t)N_NODES * 192; // 24 MB  [N,3,64]
    float* agg_s = ws; ws += (size_t)N_NODES * 64;  // 8 MB
    float* agg_v = ws; ws += (size_t)N_NODES * 192; // 24 MB
    int* counts    = (int*)ws; ws += N_NODES;       // 128 KB
    int* row_start = (int*)ws; ws += N_NODES + 4;
    int* cursor    = (int*)ws; ws += N_NODES;
    int* edge_ids  = (int*)ws; ws += N_EDGES;       // 1 MB

    edge_pre_kernel<<<N_EDGES / 256, 256, 0, stream>>>(vectors, rbf, Y1);
    init_kernel<<<N_NODES * 64 / 256, 256, 0, stream>>>(embed_s, species, s, v);

    // CSR build (once; reused by both interactions)
    hipMemsetAsync(counts, 0, N_NODES * sizeof(int), stream);
    hist_kernel<<<N_EDGES / 256, 256, 0, stream>>>(receivers, counts);
    scan_kernel<<<1, 1024, 0, stream>>>(counts, row_start, cursor);
    scatter_kernel<<<N_EDGES / 256, 256, 0, stream>>>(receivers, cursor, edge_ids);

    for (int i = 0; i < 2; ++i) {
        gather_kernel<<<N_NODES / 16, 256, 0, stream>>>(
            rbf, Y1, senders, edge_ids, row_start, s, v, Wr + i * 2560,
            agg_s, agg_v, (i == 0) ? 1 : 0);
        node_kernel<<<N_NODES / 16, 256, 0, stream>>>(
            agg_s, agg_v, s, v,
            Wls + i * 4096, Wlv + i * 4096, skip_s, skip_v,
            pw + i * 5760, Wps + i * 4096, Wpv + i * 4096,
            Wread0, Wr1a, Wr1b, species, out,
            (i > 0) ? 1 : 0, (i == 1) ? 1 : 0, i);
    }
}